// Round 3
// baseline (477.237 us; speedup 1.0000x reference)
//
#include <hip/hip_runtime.h>
#include <math.h>

#define DIM   1024
#define NV    512
#define VD    256
#define NTOK  32768

// Output layout (floats): out | soft | perp | gumbel
#define SOFT_OFF  8388608u    // 32768*256
#define PERP_OFF  25165824u   // + 32768*512
#define GUM_OFF   25165825u   // + 1  (odd -> only 4B aligned!)

#define LO_SCALE      4096.0f
#define INV_LO_SCALE  (1.0f / 4096.0f)

typedef __attribute__((ext_vector_type(4)))  _Float16 half4;
typedef __attribute__((ext_vector_type(8)))  _Float16 half8;
typedef __attribute__((ext_vector_type(16))) float    float16v;

// d_ws layout: Whi (1MB f16, k-blocked) | Wlo (1MB f16, k-blocked) | sums
#define WLO_ELEM_OFF  (NV * DIM)
#define SUMS_BYTE_OFF (2u * NV * DIM * 2u)

// ---------------------------------------------------------------------------
// K0: split W (fp32) into f16 hi/lo planes, k-blocked by 8:
//     half index = ((k>>3)*NV + var)*8 + (k&7)
// Step t (BK=16) covers chunks 2t, 2t+1; a wave's fragment read is a fully
// coalesced 512B segment per p-tile.
// ---------------------------------------------------------------------------
__global__ __launch_bounds__(256) void k_wsplit(const float* __restrict__ W,
                                                _Float16* __restrict__ whi,
                                                _Float16* __restrict__ wlo) {
    const int i   = (blockIdx.x * 256 + threadIdx.x) * 4;
    const int var = i >> 10;
    const int k   = i & 1023;
    float4 w = *(const float4*)(W + i);
    _Float16 h0 = (_Float16)w.x, h1 = (_Float16)w.y, h2 = (_Float16)w.z, h3 = (_Float16)w.w;
    _Float16 l0 = (_Float16)((w.x - (float)h0) * LO_SCALE);
    _Float16 l1 = (_Float16)((w.y - (float)h1) * LO_SCALE);
    _Float16 l2 = (_Float16)((w.z - (float)h2) * LO_SCALE);
    _Float16 l3 = (_Float16)((w.w - (float)h3) * LO_SCALE);
    const int dst = ((k >> 3) * NV + var) * 8 + (k & 7);   // k 4-aligned -> one chunk
    *(half4*)(whi + dst) = (half4){h0, h1, h2, h3};
    *(half4*)(wlo + dst) = (half4){l0, l1, l2, l3};
}

// ---------------------------------------------------------------------------
// K1: fused logits(32x512) -> softmax/argmax/one-hot/codebook/colsum.
// Barrier-free K-loop: B fragments read straight from global (W planes are
// L2-resident, coalesced 512B segments), A read per-lane straight from x
// (lane(lm,hi) -> x[m0+lm][t*16+hi*8..+7], hi pair covers full 64B lines)
// and split to f16 hi/lo in registers. B double-buffered 1 step ahead (L2),
// A 2 steps ahead (HBM). No LDS, no __syncthreads in the loop.
// Split-precision f16 math identical to the previously passing kernel.
// ---------------------------------------------------------------------------
#define LOADB(t, bh_, bl_) do {                               \
    const size_t o_ = (size_t)(t) * 8192;                     \
    bh_[0] = *(const half8*)(bhp + o_);                       \
    bh_[1] = *(const half8*)(bhp + o_ + 256);                 \
    bh_[2] = *(const half8*)(bhp + o_ + 512);                 \
    bh_[3] = *(const half8*)(bhp + o_ + 768);                 \
    bl_[0] = *(const half8*)(blp + o_);                       \
    bl_[1] = *(const half8*)(blp + o_ + 256);                 \
    bl_[2] = *(const half8*)(blp + o_ + 512);                 \
    bl_[3] = *(const half8*)(blp + o_ + 768);                 \
} while (0)

#define LOADA(t, a0_, a1_) do {                               \
    a0_ = *(const float4*)(axp + (size_t)(t) * 16);           \
    a1_ = *(const float4*)(axp + (size_t)(t) * 16 + 4);       \
} while (0)

#define CVTA(a0_, a1_, ah_, al_) do {                                         \
    float f_[8] = {a0_.x, a0_.y, a0_.z, a0_.w, a1_.x, a1_.y, a1_.z, a1_.w};   \
    _Float16 h_[8], l_[8];                                                    \
    _Pragma("unroll")                                                         \
    for (int j_ = 0; j_ < 8; ++j_) {                                          \
        h_[j_] = (_Float16)f_[j_];                                            \
        l_[j_] = (_Float16)((f_[j_] - (float)h_[j_]) * LO_SCALE);             \
    }                                                                         \
    ah_ = (half8){h_[0], h_[1], h_[2], h_[3], h_[4], h_[5], h_[6], h_[7]};    \
    al_ = (half8){l_[0], l_[1], l_[2], l_[3], l_[4], l_[5], l_[6], l_[7]};    \
} while (0)

#define STEP(ah_, al_, bh_, bl_) do {                                                   \
    _Pragma("unroll")                                                                   \
    for (int p_ = 0; p_ < 4; ++p_) {                                                    \
        accM[p_] = __builtin_amdgcn_mfma_f32_32x32x16_f16(ah_, bh_[p_], accM[p_], 0, 0, 0); \
        accC[p_] = __builtin_amdgcn_mfma_f32_32x32x16_f16(ah_, bl_[p_], accC[p_], 0, 0, 0); \
        accC[p_] = __builtin_amdgcn_mfma_f32_32x32x16_f16(al_, bh_[p_], accC[p_], 0, 0, 0); \
    }                                                                                   \
} while (0)

__global__ __launch_bounds__(256, 2) void k_fused(
        const float* __restrict__ x,
        const _Float16* __restrict__ whi,
        const _Float16* __restrict__ wlo,
        const float* __restrict__ mask,
        const float* __restrict__ codebook,
        float* __restrict__ soft,
        float* __restrict__ gumbel,
        float* __restrict__ outp,
        float* __restrict__ sums) {
    __shared__ float ep[960];              // epilogue scratch only (3.84 KB)

    const int tid  = threadIdx.x;
    const int lane = tid & 63;
    const int wave = tid >> 6;
    const int lm   = lane & 31;
    const int hi   = lane >> 5;
    const int m0   = blockIdx.x * 32;

    float16v accM[4], accC[4];
#pragma unroll
    for (int p = 0; p < 4; ++p) { accM[p] = (float16v)(0.0f); accC[p] = (float16v)(0.0f); }

    // per-lane global bases
    const float*    axp = x   + (size_t)(m0 + lm) * DIM + hi * 8;
    const _Float16* bhp = whi + (size_t)(hi * 512 + wave * 128 + lm) * 8;
    const _Float16* blp = wlo + (size_t)(hi * 512 + wave * 128 + lm) * 8;

    half8 bhA[4], blA[4], bhB[4], blB[4];
    float4 aA0, aA1, aB0, aB1;
    half8 ah, al;

    LOADA(0, aA0, aA1);
    LOADA(1, aB0, aB1);
    LOADB(0, bhA, blA);

    for (int tt = 0; tt < 32; ++tt) {
        const int t0 = tt * 2;
        LOADB(t0 + 1, bhB, blB);                               // 1 step ahead (L2)
        CVTA(aA0, aA1, ah, al);
        { const int tn = (t0 + 2 < 64) ? t0 + 2 : 0; LOADA(tn, aA0, aA1); }  // 2 ahead (HBM)
        STEP(ah, al, bhA, blA);
        { const int tn = (t0 + 2 < 64) ? t0 + 2 : 0; LOADB(tn, bhA, blA); }
        CVTA(aB0, aB1, ah, al);
        { const int tn = (t0 + 3 < 64) ? t0 + 3 : 1; LOADA(tn, aB0, aB1); }
        STEP(ah, al, bhB, blB);
    }

    // ---------------- fused epilogue (verbatim from passing kernel) ----------------
    float* smaxA = ep;                     // [4][32]
    float* ssumA = ep + 128;               // [4][32]
    int*   sidxA = (int*)(ep + 256);       // [4][32]
    float* scol  = ep + 384;               // [512]
    int*   skidx = (int*)(ep + 896);       // [32]
    float* smask = ep + 928;               // [32]

    if (tid < 32) smask[tid] = mask[m0 + tid];
    __syncthreads();

    // token row per (r, hi): row = (r&3) + 8*(r>>2) + 4*hi  (32x32 MFMA C-layout)
    int rowv[16];
#pragma unroll
    for (int r = 0; r < 16; ++r) rowv[r] = (r & 3) + 8 * (r >> 2) + 4 * hi;

    float mk[16];
#pragma unroll
    for (int r = 0; r < 16; ++r) mk[r] = smask[rowv[r]];

    // logits (identical math to prior kernel) + mask + col0 zero
    float v[4][16];
#pragma unroll
    for (int p = 0; p < 4; ++p)
#pragma unroll
        for (int r = 0; r < 16; ++r) {
            float tv = (accM[p][r] + accC[p][r] * INV_LO_SCALE) * mk[r];
            if (wave == 0 && p == 0 && lm == 0) tv = 0.0f;   // var 0
            v[p][r] = tv;
        }

    // argmax (first index on ties): over p in-thread, then butterfly over lm
    float bv[16]; int bi[16];
#pragma unroll
    for (int r = 0; r < 16; ++r) { bv[r] = v[0][r]; bi[r] = wave * 128 + lm; }
#pragma unroll
    for (int p = 1; p < 4; ++p)
#pragma unroll
        for (int r = 0; r < 16; ++r)
            if (v[p][r] > bv[r]) { bv[r] = v[p][r]; bi[r] = wave * 128 + p * 32 + lm; }
#pragma unroll
    for (int off = 16; off >= 1; off >>= 1)
#pragma unroll
        for (int r = 0; r < 16; ++r) {
            float ov = __shfl_xor(bv[r], off, 64);
            int   oi = __shfl_xor(bi[r], off, 64);
            if (ov > bv[r] || (ov == bv[r] && oi < bi[r])) { bv[r] = ov; bi[r] = oi; }
        }
    if (lm == 0)
#pragma unroll
        for (int r = 0; r < 16; ++r) {
            smaxA[wave * 32 + rowv[r]] = bv[r];
            sidxA[wave * 32 + rowv[r]] = bi[r];
        }
    __syncthreads();

    // combine 4 wave-partials (ascending var ranges keep first-index semantics)
    float mx[16]; int kk[16];
#pragma unroll
    for (int r = 0; r < 16; ++r) {
        mx[r] = smaxA[rowv[r]]; kk[r] = sidxA[rowv[r]];
#pragma unroll
        for (int w2 = 1; w2 < 4; ++w2) {
            float mv = smaxA[w2 * 32 + rowv[r]];
            int   iv = sidxA[w2 * 32 + rowv[r]];
            if (mv > mx[r] || (mv == mx[r] && iv < kk[r])) { mx[r] = mv; kk[r] = iv; }
        }
    }

    // exp + row-sum
    float rs[16];
#pragma unroll
    for (int r = 0; r < 16; ++r) rs[r] = 0.0f;
#pragma unroll
    for (int p = 0; p < 4; ++p)
#pragma unroll
        for (int r = 0; r < 16; ++r) {
            v[p][r] = __expf(v[p][r] - mx[r]);
            rs[r] += v[p][r];
        }
#pragma unroll
    for (int off = 16; off >= 1; off >>= 1)
#pragma unroll
        for (int r = 0; r < 16; ++r) rs[r] += __shfl_xor(rs[r], off, 64);
    if (lm == 0)
#pragma unroll
        for (int r = 0; r < 16; ++r) ssumA[wave * 32 + rowv[r]] = rs[r];
    if (wave == 0 && lm == 0)
#pragma unroll
        for (int r = 0; r < 16; ++r) skidx[rowv[r]] = kk[r];
    __syncthreads();

    float inv_[16];
#pragma unroll
    for (int r = 0; r < 16; ++r)
        inv_[r] = 1.0f / (ssumA[rowv[r]] + ssumA[32 + rowv[r]] +
                          ssumA[64 + rowv[r]] + ssumA[96 + rowv[r]]);

    // soft stores + masked column partial sums
    float ca[4] = {0.f, 0.f, 0.f, 0.f};
#pragma unroll
    for (int p = 0; p < 4; ++p)
#pragma unroll
        for (int r = 0; r < 16; ++r) {
            float sv = v[p][r] * inv_[r];
            soft[(size_t)(m0 + rowv[r]) * NV + wave * 128 + p * 32 + lm] = sv;
            ca[p] += sv * mk[r];
        }
#pragma unroll
    for (int p = 0; p < 4; ++p) ca[p] += __shfl_xor(ca[p], 32, 64);
    if (hi == 0)
#pragma unroll
        for (int p = 0; p < 4; ++p) scol[wave * 128 + p * 32 + lm] = ca[p];

    // one-hot + codebook gather (skidx valid since last barrier)
#pragma unroll
    for (int s = 0; s < 8; ++s) {
        const int tk = wave * 8 + s;
        const int k  = skidx[tk];
        float* grow = gumbel + (size_t)(m0 + tk) * NV;   // 4B-aligned base
#pragma unroll
        for (int j = 0; j < 8; ++j)
            grow[j * 64 + lane] = (j * 64 + lane == k) ? 1.0f : 0.0f;
        float4 cv;
        if (k == 0) { cv.x = cv.y = cv.z = cv.w = 0.0f; }
        else        { cv = *(const float4*)(codebook + (size_t)k * VD + lane * 4); }
        *(float4*)(outp + (size_t)(m0 + tk) * VD + lane * 4) = cv;
    }

    __syncthreads();   // scol complete
    atomicAdd(&sums[tid],       scol[tid]);
    atomicAdd(&sums[tid + 256], scol[tid + 256]);
    if (wave == 0) {
        float mv = (lane < 32) ? smask[lane] : 0.0f;
#pragma unroll
        for (int off = 32; off >= 1; off >>= 1) mv += __shfl_xor(mv, off, 64);
        if (lane == 0) atomicAdd(&sums[NV], mv);
    }
}

// ---------------------------------------------------------------------------
// K2: perplexity from 513 accumulated floats
// ---------------------------------------------------------------------------
__global__ __launch_bounds__(256) void k_perp(const float* __restrict__ sums,
                                              float* __restrict__ perp) {
    __shared__ float red[256];
    const int tid = threadIdx.x;
    const float msum = sums[NV];
    float ent = 0.f;
    for (int c = tid; c < NV; c += 256) {
        const float a = sums[c] / msum;
        ent += a * logf(a + 1e-7f);
    }
    red[tid] = ent;
    __syncthreads();
    for (int s = 128; s > 0; s >>= 1) {
        if (tid < s) red[tid] += red[tid + s];
        __syncthreads();
    }
    if (tid == 0) perp[0] = expf(-red[0]);
}

// ---------------------------------------------------------------------------
extern "C" void kernel_launch(void* const* d_in, const int* in_sizes, int n_in,
                              void* d_out, int out_size, void* d_ws, size_t ws_size,
                              hipStream_t stream) {
    const float* x    = (const float*)d_in[0];
    const float* mask = (const float*)d_in[1];
    const float* W    = (const float*)d_in[2];
    const float* cb   = (const float*)d_in[3];

    float* out    = (float*)d_out;
    float* soft   = out + SOFT_OFF;
    float* perp   = out + PERP_OFF;
    float* gumbel = out + GUM_OFF;

    _Float16* whi = (_Float16*)d_ws;
    _Float16* wlo = whi + WLO_ELEM_OFF;
    float* sums   = (float*)((char*)d_ws + SUMS_BYTE_OFF);

    hipMemsetAsync(sums, 0, (NV + 1) * sizeof(float), stream);

    k_wsplit<<<NV * DIM / (256 * 4), 256, 0, stream>>>(W, whi, wlo);
    k_fused<<<NTOK / 32, 256, 0, stream>>>(x, whi, wlo, mask, cb, soft, gumbel, out, sums);
    k_perp<<<1, 256, 0, stream>>>(sums, perp);
}